// Round 13
// baseline (7534.984 us; speedup 1.0000x reference)
//
#include <hip/hip_runtime.h>
#include <hip/hip_bf16.h>

// Problem: B=64, S=512, D=1024, gates N=4096, K=2048 (x ++ h)

typedef __attribute__((ext_vector_type(8))) short bf16x8;
typedef __attribute__((ext_vector_type(16))) float f32x16;
typedef __attribute__((ext_vector_type(4)))  int   i32x4;
typedef __attribute__((ext_vector_type(4)))  float f32x4;

#define AT_RLX __ATOMIC_RELAXED
#define SC_AGT __HIP_MEMORY_SCOPE_AGENT

struct U2 { unsigned long long a, b; };
#define BF16SENT4 0x7FC07FC07FC07FC0ULL   // 4x bf16 NaN
#define F32SENT2  0x7FC000007FC00000ULL   // 2x f32 NaN

// ---------- prep kernels ----------

// Wt[n*2048 + k] = bf16(W[k*4096 + n])   (B^T layout: 8 consecutive k per lane)
__global__ __launch_bounds__(256) void conv_w(const float* __restrict__ W,
                                              __hip_bfloat16* __restrict__ Wt) {
    size_t id = (size_t)blockIdx.x * 256 + threadIdx.x;   // < 2048*4096
    int k = (int)(id >> 12);
    int n = (int)(id & 4095);
    Wt[(size_t)n * 2048 + k] = __float2bfloat16(W[id]);
}

// Xt[(s*64+b)*1024 + d] = bf16(X[(b*512+s)*1024 + d])
__global__ __launch_bounds__(256) void conv_x(const float* __restrict__ X,
                                              __hip_bfloat16* __restrict__ Xt) {
    size_t id = (size_t)blockIdx.x * 256 + threadIdx.x;   // < 64*512*1024
    int d   = (int)(id & 1023);
    int row = (int)(id >> 10);
    int s = row >> 6;
    int b = row & 63;
    Xt[id] = __float2bfloat16(X[(((size_t)b * 512 + s) << 10) + d]);
}

// Pre-fill sentinel rings. comb (single buffer, 262144 f32) -> all NaN.
// hring [3][64][1024] bf16: slots 0,1 -> NaN; slot 2 -> h(-1) = bf16(hx) broadcast.
__global__ __launch_bounds__(256) void init_rings(const float* __restrict__ hx,
                                                  unsigned int* __restrict__ combu,
                                                  unsigned int* __restrict__ hru) {
    int id = blockIdx.x * 256 + threadIdx.x;              // grid 1408 -> 360448
    if (id >= 360448) return;
    if (id < 262144) { combu[id] = 0x7FC00000u; return; }
    int j = id - 262144;                                  // < 98304 (h ring as u32)
    if (j < 65536) { hru[j] = 0x7FC07FC0u; return; }      // slots 0,1 -> NaN
    int j2 = j - 65536;                                   // slot 2: h(-1), 32768 u32
    int d = (j2 & 511) * 2;
    unsigned int lo = __builtin_bit_cast(unsigned short, __float2bfloat16(hx[d]));
    unsigned int hi = __builtin_bit_cast(unsigned short, __float2bfloat16(hx[d + 1]));
    hru[65536 + j2] = lo | (hi << 16);
}

// ---------- coherence-point primitives ----------
// 16B IF-coherent load (sc0 sc1). Caller must vm_wait0() before consuming.
__device__ __forceinline__ i32x4 ld_cp16(const void* p) {
    i32x4 r;
    asm volatile("global_load_dwordx4 %0, %1, off sc0 sc1"
                 : "=&v"(r) : "v"(p) : "memory");
    return r;
}
__device__ __forceinline__ void vm_wait0() {
    asm volatile("s_waitcnt vmcnt(0)" ::: "memory");
    __builtin_amdgcn_sched_barrier(0);
}
// 8B write EXECUTED AT the IF coherence point: returning agent-scope exchange.
__device__ __forceinline__ void xchg8f(float* p, float lo, float hi) {
    union { float f[2]; unsigned long long u; } c;
    c.f[0] = lo; c.f[1] = hi;
    unsigned long long old =
        __hip_atomic_exchange((unsigned long long*)p, c.u, AT_RLX, SC_AGT);
    asm volatile("" :: "v"(old));
}
__device__ __forceinline__ void xchg8u(unsigned long long* p, unsigned long long v) {
    unsigned long long old = __hip_atomic_exchange(p, v, AT_RLX, SC_AGT);
    asm volatile("" :: "v"(old));
}

// ---------- fused persistent recurrence: SENTINEL handoff, zero flags ----------
// 256 WGs x 256 thr (1 WG/CU). WG b: nt=b>>1 (col tile), mt=b&1 (row block).
// Readiness is merged into the data: h/comb granules are NaN until written (each 8B
// chunk written atomically by ONE returning xchg; data provably finite -> NaN can
// never be data). Producers fire comb xchgs and continue (no drain, no flag);
// consumers poll data granules directly (sc0sc1, masked partial retry).
//
// DEADLOCK FIX vs r12: a __syncthreads() BETWEEN the comb poll and the resets.
// Before it, a thread could reset granules other threads were still polling
// (wiping their un-observed data -> infinite NaN spin -> grid wedge). After the
// barrier: every thread's data is in registers, and all 128 producers of this
// row-block are proven past phase 1 -> hring reset of h(s-1) row b is also safe.
//
//   comb: SINGLE buffer, sole reader resets after the barrier; producer's
//   comb(s+1) write is gated on h(s), which is published only after the resets
//   are drained (vmcnt0 at the reduction barrier) -> always lands on NaN.
//   hring: depth-3; slot timeline publish(s) -> read(s+1) -> reset(s+1) ->
//   publish(s+3): one step of slack.
// LDS double-buffered (s&1) so no post-publish barrier is needed.
__global__ __launch_bounds__(256, 1) void lstm_fused(
    const __hip_bfloat16* __restrict__ Xt,
    const __hip_bfloat16* __restrict__ Wt,
    const float* __restrict__ bias,
    const float* __restrict__ lnw,
    const float* __restrict__ lnb,
    const float* __restrict__ cx,
    float* __restrict__ comb,            // [64][4096] f32, NaN-prefilled
    unsigned short* __restrict__ hring,  // [3][64][1024] bf16
    float* __restrict__ out)
{
    const int tid  = threadIdx.x;
    const int lane = tid & 63;
    const int wv   = tid >> 6;          // wave in WG: 0..3
    const int b    = blockIdx.x;        // 0..255

    const int nt = b >> 1;              // col tile 0..127
    const int mt = b & 1;               // row block 0..1
    const int kc = wv;                  // K chunk 0..3  (512 each)
    const int cl = lane & 31;
    const int kh = (lane >> 5) * 8;
    const int n0 = nt * 32;

    __shared__ float lds_f[8192];       // double-buffered 4 x 32 x 32 partials
    __shared__ float red[8];

    // ---- load this wave's B chunk into registers, once ----
    const short* bp = (const short*)Wt + (size_t)(n0 + cl) * 2048 + kc * 512 + kh;
    bf16x8 breg[32];
#pragma unroll
    for (int i = 0; i < 32; ++i) breg[i] = *(const bf16x8*)(bp + i * 16);

    // ---- A pointers ----
    const short* xbase = (const short*)Xt + (size_t)(mt * 32 + cl) * 1024 + kc * 512 + kh;
    const unsigned short* hrow = hring + (mt * 32 + cl) * 1024 + (kc - 2) * 512 + kh; // kc>=2

    // ---- pointwise persistent state + parameter preloads (rows owned by WGs 0..63) ----
    // thread t owns 4 consecutive outputs o = 4t..4t+3.
    float cr[4];
    f32x4 bias_r[4], lnw_r[4], lnb_r[4];
    if (b < 64) {
#pragma unroll
        for (int e = 0; e < 4; ++e) cr[e] = cx[4 * tid + e];
#pragma unroll
        for (int g = 0; g < 4; ++g) {
            bias_r[g] = *(const f32x4*)&bias[1024 * g + 4 * tid];
            lnw_r[g]  = *(const f32x4*)&lnw[1024 * g + 4 * tid];
            lnb_r[g]  = *(const f32x4*)&lnb[1024 * g + 4 * tid];
        }
    }

    int sr = 2;   // hring slot of h(s-1) (also this step's reset target)
    int sw = 0;   // hring slot of h(s)

    for (int s = 0; s < 512; ++s) {
        // ================= phase 1: GEMM, split-K reduced in LDS =================
        f32x16 accA, accB;
#pragma unroll
        for (int i = 0; i < 16; ++i) { accA[i] = 0.f; accB[i] = 0.f; }
        if (kc < 2) {
            const short* ap = xbase + (size_t)s * 65536;
#pragma unroll
            for (int i = 0; i < 16; ++i) {
                bf16x8 a0 = *(const bf16x8*)(ap + i * 16);
                bf16x8 a1 = *(const bf16x8*)(ap + (i + 16) * 16);
                accA = __builtin_amdgcn_mfma_f32_32x32x16_bf16(a0, breg[i],      accA, 0, 0, 0);
                accB = __builtin_amdgcn_mfma_f32_32x32x16_bf16(a1, breg[i + 16], accB, 0, 0, 0);
            }
        } else {
            // h(s-1): poll the DATA granules until they stop being NaN (masked retry)
            const unsigned short* hp = hrow + sr * 65536;
            bf16x8 ha[32];
            unsigned int miss = 0xFFFFFFFFu;
            for (;;) {
#pragma unroll
                for (int i = 0; i < 32; ++i)
                    if (miss & (1u << i))
                        ha[i] = __builtin_bit_cast(bf16x8, ld_cp16(hp + i * 16));
                vm_wait0();
                unsigned int nm = 0;
#pragma unroll
                for (int i = 0; i < 32; ++i)
                    if (miss & (1u << i)) {
                        U2 c = __builtin_bit_cast(U2, ha[i]);
                        if (c.a == BF16SENT4 || c.b == BF16SENT4) nm |= 1u << i;
                    }
                miss = nm;
                if (!miss) break;
                __builtin_amdgcn_s_sleep(1);
            }
#pragma unroll
            for (int i = 0; i < 16; ++i) {
                accA = __builtin_amdgcn_mfma_f32_32x32x16_bf16(ha[i],      breg[i],      accA, 0, 0, 0);
                accB = __builtin_amdgcn_mfma_f32_32x32x16_bf16(ha[i + 16], breg[i + 16], accB, 0, 0, 0);
            }
        }
        float* lbuf = lds_f + (s & 1) * 4096;
#pragma unroll
        for (int r = 0; r < 16; ++r) {
            int rl = (r & 3) + 8 * (r >> 2) + 4 * (lane >> 5);
            lbuf[kc * 1024 + rl * 32 + cl] = accA[r] + accB[r];
        }
        __syncthreads();
        {
            // publish comb tile: fire-and-forget returning xchgs (no drain, no flag)
            float* crow = comb + (size_t)(mt * 32) * 4096 + n0;
#pragma unroll
            for (int half = 0; half < 2; ++half) {
                int e = 2 * tid + half * 512;           // even -> 8B aligned pair
                float2 p0 = *(const float2*)&lbuf[e];
                float2 p1 = *(const float2*)&lbuf[1024 + e];
                float2 p2 = *(const float2*)&lbuf[2048 + e];
                float2 p3 = *(const float2*)&lbuf[3072 + e];
                xchg8f(&crow[(size_t)(e >> 5) * 4096 + (e & 31)],
                       p0.x + p1.x + p2.x + p3.x,
                       p0.y + p1.y + p2.y + p3.y);
            }
        }
        // no barrier: LDS is double-buffered; next step writes the other half

        // ================= phase 2: pointwise (rows on WGs 0..63) =================
        if (b < 64) {
            const float* c0 = comb + (size_t)b * 4096;
            f32x4 xv[4];
            unsigned int miss = 0xFu;
            for (;;) {
#pragma unroll
                for (int g = 0; g < 4; ++g)
                    if (miss & (1u << g))
                        xv[g] = __builtin_bit_cast(f32x4, ld_cp16(&c0[1024 * g + 4 * tid]));
                vm_wait0();
                unsigned int nm = 0;
#pragma unroll
                for (int g = 0; g < 4; ++g)
                    if (miss & (1u << g)) {
                        U2 c = __builtin_bit_cast(U2, xv[g]);
                        if (c.a == F32SENT2 || c.b == F32SENT2) nm |= 1u << g;
                    }
                miss = nm;
                if (!miss) break;
                __builtin_amdgcn_s_sleep(1);
            }
            // ---- DEADLOCK FIX: all threads must finish polling before ANY reset ----
            __syncthreads();
            // Now safe: every thread's granules are in registers, and all producers
            // of this row-block are past phase 1 (their tile-publish follows their
            // internal barrier) -> done reading h(s-1) row b.
            {
                float* crst = (float*)c0 + 16 * tid;
#pragma unroll
                for (int j = 0; j < 8; ++j)
                    xchg8u((unsigned long long*)(crst + 2 * j), F32SENT2);
                xchg8u((unsigned long long*)(hring + sr * 65536 + b * 1024 + 4 * tid),
                       BF16SENT4);
            }
            float v[4][4];
            float s1 = 0.f, s2 = 0.f;
#pragma unroll
            for (int g = 0; g < 4; ++g)
#pragma unroll
                for (int e = 0; e < 4; ++e) {
                    float x = xv[g][e] + bias_r[g][e];
                    v[g][e] = x;
                    s1 += x;
                    s2 += x * x;
                }
            for (int off = 32; off; off >>= 1) {
                s1 += __shfl_down(s1, off);
                s2 += __shfl_down(s2, off);
            }
            if (lane == 0) { red[2 * wv] = s1; red[2 * wv + 1] = s2; }
            __syncthreads();   // also drains the reset xchgs (vmcnt 0 at barrier)
            float sum = red[0] + red[2] + red[4] + red[6];
            float ssq = red[1] + red[3] + red[5] + red[7];
            float mean = sum * (1.f / 4096.f);
            float var  = ssq * (1.f / 4096.f) - mean * mean;
            float rstd = rsqrtf(var + 1e-5f);
            float hn[4];
#pragma unroll
            for (int e = 0; e < 4; ++e) {
                float yi = (v[0][e] - mean) * rstd * lnw_r[0][e] + lnb_r[0][e];
                float yf = (v[1][e] - mean) * rstd * lnw_r[1][e] + lnb_r[1][e];
                float yo = (v[2][e] - mean) * rstd * lnw_r[2][e] + lnb_r[2][e];
                float yh = (v[3][e] - mean) * rstd * lnw_r[3][e] + lnb_r[3][e];
                float ig = 1.f / (1.f + __expf(-yi));
                float fg = 1.f / (1.f + __expf(-yf));
                float og = 1.f / (1.f + __expf(-yo));
                float hd = tanhf(yh);
                float cn = fg * cr[e] + ig * hd;
                cr[e] = cn;
                hn[e] = og * tanhf(cn);
            }
            // publish h(s): ONE 8B returning xchg (outputs 4t..4t+3). Publication
            // IS the readiness signal. Then the out store, off the critical path.
            unsigned long long hp8 = 0;
#pragma unroll
            for (int e = 0; e < 4; ++e)
                hp8 |= (unsigned long long)
                       __builtin_bit_cast(unsigned short, __float2bfloat16(hn[e])) << (16 * e);
            xchg8u((unsigned long long*)(hring + sw * 65536 + b * 1024 + 4 * tid), hp8);
            f32x4 o4;
#pragma unroll
            for (int e = 0; e < 4; ++e) o4[e] = hn[e];
            *(f32x4*)(out + (size_t)b * 524288 + (size_t)s * 1024 + 4 * tid) = o4;
        }
        sr = (sr == 2) ? 0 : sr + 1;
        sw = (sw == 2) ? 0 : sw + 1;
    }
}

// ---------- launcher ----------
extern "C" void kernel_launch(void* const* d_in, const int* in_sizes, int n_in,
                              void* d_out, int out_size, void* d_ws, size_t ws_size,
                              hipStream_t stream) {
    const float* X   = (const float*)d_in[0];   // [64,512,1024]
    const float* W   = (const float*)d_in[1];   // [2048,4096]
    const float* bv  = (const float*)d_in[2];   // [4096]
    const float* lnw = (const float*)d_in[3];   // [4096]
    const float* lnb = (const float*)d_in[4];   // [4096]
    const float* hx  = (const float*)d_in[5];   // [1,1024]
    const float* cx  = (const float*)d_in[6];   // [1,1024]
    float* out = (float*)d_out;                 // [64,512,1024]

    char* base = (char*)d_ws;
    __hip_bfloat16* Wt    = (__hip_bfloat16*)(base);                 // 16 MB
    __hip_bfloat16* Xt    = (__hip_bfloat16*)(base + 16777216);      // 64 MB
    float*          comb  = (float*)         (base + 83886080);      // 1 MB (NaN-prefilled)
    unsigned short* hring = (unsigned short*)(base + 84934656);      // 384 KB ([3][64][1024])
    // total = 85,327,872 B

    conv_w<<<32768, 256, 0, stream>>>(W, Wt);
    conv_x<<<131072, 256, 0, stream>>>(X, Xt);
    init_rings<<<1408, 256, 0, stream>>>(hx, (unsigned int*)comb, (unsigned int*)hring);

    lstm_fused<<<256, 256, 0, stream>>>(Xt, Wt, bv, lnw, lnb, cx, comb, hring, out);
}

// Round 14
// 5568.471 us; speedup vs baseline: 1.3532x; 1.3532x over previous
//
#include <hip/hip_runtime.h>
#include <hip/hip_bf16.h>

// Problem: B=64, S=512, D=1024, gates N=4096, K=2048 (x ++ h)

typedef __attribute__((ext_vector_type(8))) short bf16x8;
typedef __attribute__((ext_vector_type(16))) float f32x16;
typedef __attribute__((ext_vector_type(4)))  int   i32x4;

#define AT_RLX __ATOMIC_RELAXED
#define SC_AGT __HIP_MEMORY_SCOPE_AGENT

// ---------- prep kernels ----------

// Wt[n*2048 + k] = bf16(W[k*4096 + n])   (B^T layout: 8 consecutive k per lane)
__global__ __launch_bounds__(256) void conv_w(const float* __restrict__ W,
                                              __hip_bfloat16* __restrict__ Wt) {
    size_t id = (size_t)blockIdx.x * 256 + threadIdx.x;   // < 2048*4096
    int k = (int)(id >> 12);
    int n = (int)(id & 4095);
    Wt[(size_t)n * 2048 + k] = __float2bfloat16(W[id]);
}

// Xt[(s*64+b)*1024 + d] = bf16(X[(b*512+s)*1024 + d])
__global__ __launch_bounds__(256) void conv_x(const float* __restrict__ X,
                                              __hip_bfloat16* __restrict__ Xt) {
    size_t id = (size_t)blockIdx.x * 256 + threadIdx.x;   // < 64*512*1024
    int d   = (int)(id & 1023);
    int row = (int)(id >> 10);
    int s = row >> 6;
    int b = row & 63;
    Xt[id] = __float2bfloat16(X[(((size_t)b * 512 + s) << 10) + d]);
}

// zero comb2 epoch-granules (epoch 0 = "no step published"); prefill h(-1); zero hflag
__global__ __launch_bounds__(256) void init_misc(const float* __restrict__ hx,
                                                 __hip_bfloat16* __restrict__ h,
                                                 unsigned long long* __restrict__ comb2,
                                                 unsigned int* __restrict__ hflag) {
    int id = blockIdx.x * 256 + threadIdx.x;              // grid 1024 -> 262144
    comb2[id] = 0ULL;
    if (id < 65536) h[id] = __float2bfloat16(hx[id & 1023]);
    if (id < 1024)  hflag[id] = 0u;
}

// ---------- coherence-point primitives ----------
// 16B IF-coherent load (sc0 sc1). Caller must vm_wait0() before consuming.
__device__ __forceinline__ i32x4 ld_cp16(const void* p) {
    i32x4 r;
    asm volatile("global_load_dwordx4 %0, %1, off sc0 sc1"
                 : "=&v"(r) : "v"(p) : "memory");
    return r;
}
__device__ __forceinline__ void vm_wait0() {
    asm volatile("s_waitcnt vmcnt(0)" ::: "memory");
    __builtin_amdgcn_sched_barrier(0);
}
// 8B write EXECUTED AT the IF coherence point: returning agent-scope exchange.
// vmcnt clears only when the old value returns from IF (round-5 lesson). Used ONLY
// for the h publish (it precedes a separate flag, which needs proven arrival).
__device__ __forceinline__ void xchg8u(unsigned long long* p, unsigned long long v) {
    unsigned long long old = __hip_atomic_exchange(p, v, AT_RLX, SC_AGT);
    asm volatile("" :: "v"(old));
}

// ---------- fused persistent recurrence ----------
// 256 WGs x 256 thr (1 WG/CU). WG b: nt=b>>1 (col tile), mt=b&1 (row block).
//
// comb hop = EPOCH GRANULES (new): comb2[row][col] is a u64 {lo32 = f32 value,
// hi32 = epoch = s+1}. Producer publishes with plain 8B atomic stores (naturally
// atomic, fire-and-forget: NO drain, NO flag, NO reset — epoch is monotone).
// Consumer polls its own 16 granules: readiness and data arrive in the same load.
// r13's sentinel failure (reset traffic) is structurally eliminated.
//
// h hop = r10's proven path: consumer publishes h via returning-xchg + drain +
// hflag; producer h-waves poll hflag per-lane then batch 32x16B sc loads.
//
// WAR safety: consumer's reduce barrier collectively confirms all 128 producers
// of its row-block published comb(s) (thread t's granules map to producers
// nt=32g+(t>>3), spanning all 128) => they finished reading h(s-1) => h(s)
// overwrite is safe. Producer writes comb(s+1) only after seeing h(s) (hflag),
// which the consumer sets only after reading all its comb(s) granules.
// LDS double-buffered (s&1): no post-publish barrier.
__global__ __launch_bounds__(256, 1) void lstm_fused(
    const __hip_bfloat16* __restrict__ Xt,
    const __hip_bfloat16* __restrict__ Wt,
    __hip_bfloat16* __restrict__ h,
    const float* __restrict__ bias,
    const float* __restrict__ lnw,
    const float* __restrict__ lnb,
    const float* __restrict__ cx,
    unsigned long long* __restrict__ comb2,   // [64][4096] epoch-granules
    float* __restrict__ out,
    unsigned int* __restrict__ hflag)         // 64 x 16-u32 padded
{
    const int tid  = threadIdx.x;
    const int lane = tid & 63;
    const int wv   = tid >> 6;          // wave in WG: 0..3
    const int b    = blockIdx.x;        // 0..255

    const int nt = b >> 1;              // col tile 0..127
    const int mt = b & 1;               // row block 0..1
    const int kc = wv;                  // K chunk 0..3  (512 each)
    const int cl = lane & 31;
    const int kh = (lane >> 5) * 8;
    const int n0 = nt * 32;

    __shared__ float lds_f[8192];       // double-buffered 4 x 32 x 32 partials
    __shared__ float red[8];

    // ---- load this wave's B chunk into registers, once ----
    const short* bp = (const short*)Wt + (size_t)(n0 + cl) * 2048 + kc * 512 + kh;
    bf16x8 breg[32];
#pragma unroll
    for (int i = 0; i < 32; ++i) breg[i] = *(const bf16x8*)(bp + i * 16);

    // ---- A pointers ----
    const short* xbase = (const short*)Xt + (size_t)(mt * 32 + cl) * 1024 + kc * 512 + kh; // + s*65536
    const short* hrow  = (const short*)h  + (size_t)(mt * 32 + cl) * 1024 + (kc - 2) * 512 + kh; // kc>=2
    const unsigned int* myhf = &hflag[(mt * 32 + cl) * 16];   // h-row flag this lane reads

    // ---- pointwise persistent state + parameter preloads (rows owned by WGs 0..63) ----
    // thread t owns 4 consecutive outputs o = 4t..4t+3.
    float cr[4];
    float bias_r[4][4], lnw_r[4][4], lnb_r[4][4];
    if (b < 64) {
#pragma unroll
        for (int e = 0; e < 4; ++e) cr[e] = cx[4 * tid + e];
#pragma unroll
        for (int g = 0; g < 4; ++g)
#pragma unroll
            for (int e = 0; e < 4; ++e) {
                bias_r[g][e] = bias[1024 * g + 4 * tid + e];
                lnw_r[g][e]  = lnw[1024 * g + 4 * tid + e];
                lnb_r[g][e]  = lnb[1024 * g + 4 * tid + e];
            }
    }

    for (int s = 0; s < 512; ++s) {
        // ================= phase 1: GEMM, split-K reduced in LDS =================
        f32x16 accA, accB;
#pragma unroll
        for (int i = 0; i < 16; ++i) { accA[i] = 0.f; accB[i] = 0.f; }
        if (kc < 2) {
            const short* ap = xbase + (size_t)s * 65536;
#pragma unroll
            for (int i = 0; i < 16; ++i) {
                bf16x8 a0 = *(const bf16x8*)(ap + i * 16);
                bf16x8 a1 = *(const bf16x8*)(ap + (i + 16) * 16);
                accA = __builtin_amdgcn_mfma_f32_32x32x16_bf16(a0, breg[i],      accA, 0, 0, 0);
                accB = __builtin_amdgcn_mfma_f32_32x32x16_bf16(a1, breg[i + 16], accB, 0, 0, 0);
            }
        } else {
            // wait for h(s-1): per-lane poll of the one row flag this lane reads
            while (__hip_atomic_load(myhf, AT_RLX, SC_AGT) < (unsigned int)s)
                __builtin_amdgcn_s_sleep(1);
            asm volatile("" ::: "memory");
            // batched 16B IF-coherent loads of this lane's h row, single drain
            bf16x8 ha[32];
#pragma unroll
            for (int i = 0; i < 32; ++i)
                ha[i] = __builtin_bit_cast(bf16x8, ld_cp16(hrow + i * 16));
            vm_wait0();
#pragma unroll
            for (int i = 0; i < 16; ++i) {
                accA = __builtin_amdgcn_mfma_f32_32x32x16_bf16(ha[i],      breg[i],      accA, 0, 0, 0);
                accB = __builtin_amdgcn_mfma_f32_32x32x16_bf16(ha[i + 16], breg[i + 16], accB, 0, 0, 0);
            }
        }
        float* lbuf = lds_f + (s & 1) * 4096;
#pragma unroll
        for (int r = 0; r < 16; ++r) {
            int rl = (r & 3) + 8 * (r >> 2) + 4 * (lane >> 5);
            lbuf[kc * 1024 + rl * 32 + cl] = accA[r] + accB[r];
        }
        __syncthreads();
        {
            // publish comb tile as epoch-granules: plain 8B stores, fire-and-forget
            unsigned long long ep64 = ((unsigned long long)(unsigned)(s + 1)) << 32;
#pragma unroll
            for (int half = 0; half < 2; ++half) {
                int e = 2 * tid + half * 512;
                float2 p0 = *(const float2*)&lbuf[e];
                float2 p1 = *(const float2*)&lbuf[1024 + e];
                float2 p2 = *(const float2*)&lbuf[2048 + e];
                float2 p3 = *(const float2*)&lbuf[3072 + e];
                float v0 = p0.x + p1.x + p2.x + p3.x;
                float v1 = p0.y + p1.y + p2.y + p3.y;
                size_t g = (size_t)(mt * 32 + (e >> 5)) * 4096 + n0 + (e & 31);
                __hip_atomic_store(&comb2[g],
                    ep64 | __builtin_bit_cast(unsigned int, v0), AT_RLX, SC_AGT);
                __hip_atomic_store(&comb2[g + 1],
                    ep64 | __builtin_bit_cast(unsigned int, v1), AT_RLX, SC_AGT);
            }
        }
        // no drain, no flag, no post barrier (LDS double-buffered)

        // ================= phase 2: pointwise (rows on WGs 0..63) =================
        if (b < 64) {
            const unsigned long long* c2 = comb2 + (size_t)b * 4096;
            unsigned long long q[16];
            unsigned int miss = 0xFFFFu;
            const unsigned int tgt = (unsigned int)(s + 1);
            for (;;) {
#pragma unroll
                for (int g = 0; g < 4; ++g)
#pragma unroll
                    for (int e = 0; e < 4; ++e) {
                        int k = 4 * g + e;
                        if (miss & (1u << k))
                            q[k] = __hip_atomic_load(&c2[1024 * g + 4 * tid + e],
                                                     AT_RLX, SC_AGT);
                    }
                unsigned int nm = 0;
#pragma unroll
                for (int k = 0; k < 16; ++k)
                    if ((miss & (1u << k)) && (unsigned int)(q[k] >> 32) < tgt)
                        nm |= 1u << k;
                miss = nm;
                if (!miss) break;
                __builtin_amdgcn_s_sleep(1);
            }
            float v[4][4];
            float s1 = 0.f, s2 = 0.f;
#pragma unroll
            for (int g = 0; g < 4; ++g)
#pragma unroll
                for (int e = 0; e < 4; ++e) {
                    float x = __builtin_bit_cast(float, (unsigned int)q[4 * g + e])
                            + bias_r[g][e];
                    v[g][e] = x;
                    s1 += x;
                    s2 += x * x;
                }
            for (int off = 32; off; off >>= 1) {
                s1 += __shfl_down(s1, off);
                s2 += __shfl_down(s2, off);
            }
            if (lane == 0) { red[2 * wv] = s1; red[2 * wv + 1] = s2; }
            __syncthreads();   // collective: ALL producers of this row-block confirmed
            float sum = red[0] + red[2] + red[4] + red[6];
            float ssq = red[1] + red[3] + red[5] + red[7];
            float mean = sum * (1.f / 4096.f);
            float var  = ssq * (1.f / 4096.f) - mean * mean;
            float rstd = rsqrtf(var + 1e-5f);
            float hn[4];
#pragma unroll
            for (int e = 0; e < 4; ++e) {
                float yi = (v[0][e] - mean) * rstd * lnw_r[0][e] + lnb_r[0][e];
                float yf = (v[1][e] - mean) * rstd * lnw_r[1][e] + lnb_r[1][e];
                float yo = (v[2][e] - mean) * rstd * lnw_r[2][e] + lnb_r[2][e];
                float yh = (v[3][e] - mean) * rstd * lnw_r[3][e] + lnb_r[3][e];
                float ig = 1.f / (1.f + __expf(-yi));
                float fg = 1.f / (1.f + __expf(-yf));
                float og = 1.f / (1.f + __expf(-yo));
                float hd = tanhf(yh);
                float cn = fg * cr[e] + ig * hd;
                cr[e] = cn;
                hn[e] = og * tanhf(cn);
            }
            // h handoff (r10 path): one 8B returning xchg, drain, flag, then out
            unsigned long long hp = 0;
#pragma unroll
            for (int e = 0; e < 4; ++e)
                hp |= (unsigned long long)
                      __builtin_bit_cast(unsigned short, __float2bfloat16(hn[e])) << (16 * e);
            xchg8u((unsigned long long*)((unsigned short*)h + b * 1024 + 4 * tid), hp);
            __syncthreads();   // vmcnt(0): h(s) at coherence point
            if (tid == 0)
                __hip_atomic_store(&hflag[b * 16], (unsigned int)(s + 1), AT_RLX, SC_AGT);
            float o4[4];
#pragma unroll
            for (int e = 0; e < 4; ++e) o4[e] = hn[e];
            *(float4*)(out + (size_t)b * 524288 + (size_t)s * 1024 + 4 * tid) =
                *(float4*)o4;
        }
    }
}

// ---------- launcher ----------
extern "C" void kernel_launch(void* const* d_in, const int* in_sizes, int n_in,
                              void* d_out, int out_size, void* d_ws, size_t ws_size,
                              hipStream_t stream) {
    const float* X   = (const float*)d_in[0];   // [64,512,1024]
    const float* W   = (const float*)d_in[1];   // [2048,4096]
    const float* bv  = (const float*)d_in[2];   // [4096]
    const float* lnw = (const float*)d_in[3];   // [4096]
    const float* lnb = (const float*)d_in[4];   // [4096]
    const float* hx  = (const float*)d_in[5];   // [1,1024]
    const float* cx  = (const float*)d_in[6];   // [1,1024]
    float* out = (float*)d_out;                 // [64,512,1024]

    char* base = (char*)d_ws;
    __hip_bfloat16*     Wt    = (__hip_bfloat16*)    (base);             // 16 MB
    __hip_bfloat16*     Xt    = (__hip_bfloat16*)    (base + 16777216);  // 64 MB
    unsigned long long* comb2 = (unsigned long long*)(base + 83886080);  // 2 MB
    __hip_bfloat16*     hbuf  = (__hip_bfloat16*)    (base + 85983232);  // 128 KB
    unsigned int*       hflag = (unsigned int*)      (base + 86114304);  // 4 KB
    // total ~86.12 MB

    conv_w<<<32768, 256, 0, stream>>>(W, Wt);
    conv_x<<<131072, 256, 0, stream>>>(X, Xt);
    init_misc<<<1024, 256, 0, stream>>>(hx, hbuf, comb2, hflag);

    lstm_fused<<<256, 256, 0, stream>>>(Xt, Wt, hbuf, bv, lnw, lnb, cx, comb2, out,
                                        hflag);
}